// Round 6
// baseline (771.582 us; speedup 1.0000x reference)
//
#include <hip/hip_runtime.h>

#define DFEAT 64

// ---------------- bf16 helpers (OCP bfloat16, RNE pack) ----------------
__device__ __forceinline__ float bfhi(unsigned int u) {
    return __builtin_bit_cast(float, u & 0xFFFF0000u);
}
__device__ __forceinline__ float bflo(unsigned int u) {
    return __builtin_bit_cast(float, u << 16);
}
__device__ __forceinline__ unsigned short f2bf(float f) { // RNE
    unsigned int u = __builtin_bit_cast(unsigned int, f);
    u += 0x7FFFu + ((u >> 16) & 1u);
    return (unsigned short)(u >> 16);
}
__device__ __forceinline__ float4 upk4(uint2 v) {
    float4 r;
    r.x = bflo(v.x); r.y = bfhi(v.x);
    r.z = bflo(v.y); r.w = bfhi(v.y);
    return r;
}

// ============================================================================
// fp32 -> bf16 conversion of the input features (once per call)
// ============================================================================
__global__ void __launch_bounds__(256)
cvt_bf16_kernel(const float* __restrict__ in, unsigned short* __restrict__ outb,
                int n4) {
    int i = blockIdx.x * 256 + threadIdx.x;
    if (i >= n4) return;
    const float4 v = reinterpret_cast<const float4*>(in)[i];
    uint2 p;
    p.x = (unsigned int)f2bf(v.x) | ((unsigned int)f2bf(v.y) << 16);
    p.y = (unsigned int)f2bf(v.z) | ((unsigned int)f2bf(v.w) << 16);
    reinterpret_cast<uint2*>(outb)[i] = p;
}

// ============================================================================
// CSR build
// ============================================================================
__global__ void __launch_bounds__(256)
deg_count_kernel(const int* __restrict__ dsts, int* __restrict__ degi, int E) {
    int e = blockIdx.x * 256 + threadIdx.x;
    if (e < E) atomicAdd(&degi[dsts[e]], 1);
}

__global__ void __launch_bounds__(1024)
block_sum_kernel(const int* __restrict__ degi, int* __restrict__ bsum, int N) {
    __shared__ int sm[1024];
    int idx = blockIdx.x * 1024 + threadIdx.x;
    sm[threadIdx.x] = (idx < N) ? degi[idx] : 0;
    __syncthreads();
    for (int s = 512; s > 0; s >>= 1) {
        if (threadIdx.x < s) sm[threadIdx.x] += sm[threadIdx.x + s];
        __syncthreads();
    }
    if (threadIdx.x == 0) bsum[blockIdx.x] = sm[0];
}

__global__ void __launch_bounds__(64)
scan_bsum_kernel(int* __restrict__ bsum, int nb) {
    if (threadIdx.x == 0 && blockIdx.x == 0) {
        int run = 0;
        for (int i = 0; i < nb; ++i) { int v = bsum[i]; bsum[i] = run; run += v; }
    }
}

__global__ void __launch_bounds__(1024)
scan_final_kernel(const int* __restrict__ degi, const int* __restrict__ bsum,
                  int* __restrict__ rowptr, int* __restrict__ cursor, int N) {
    __shared__ int sm[1024];
    int idx = blockIdx.x * 1024 + threadIdx.x;
    int v = (idx < N) ? degi[idx] : 0;
    sm[threadIdx.x] = v;
    __syncthreads();
    for (int s = 1; s < 1024; s <<= 1) {
        int t = (threadIdx.x >= s) ? sm[threadIdx.x - s] : 0;
        __syncthreads();
        sm[threadIdx.x] += t;
        __syncthreads();
    }
    int excl = bsum[blockIdx.x] + sm[threadIdx.x] - v;
    if (idx < N) { rowptr[idx] = excl; cursor[idx] = excl; }
    if (idx == N - 1) rowptr[N] = excl + v;
}

// Partitioned fill: pass handles dst in [lo,hi). Active col slice per pass is
// ~6.4MB/8 = 800 KB -> a line's ~16 writes land within one epoch -> L2 can
// write-combine instead of emitting per-element 64B partial-line transactions.
__global__ void __launch_bounds__(256)
fill_pass_kernel(const int* __restrict__ srcs, const int* __restrict__ dsts,
                 int* __restrict__ cursor, int* __restrict__ col, int E,
                 int lo, int hi) {
    int e = blockIdx.x * 256 + threadIdx.x;
    if (e < E) {
        int d = dsts[e];
        if (d >= lo && d < hi) {
            int pos = atomicAdd(&cursor[d], 1);
            col[pos] = srcs[e];
        }
    }
}

// ============================================================================
// Fully fused SAGE layer, barrier-free: one wave per node.
//   gather-mean (bf16 rows, r=lane>>4 neighbor slot, c=lane&15 uint2 chunk)
//   -> per-WAVE LDS feat exchange (no __syncthreads: same-wave LDS ordering
//      is guaranteed by compiler-inserted lgkmcnt waits)
//   -> matvec vs bf16 weights in LDS (row stride 68 ushorts = 136 B: 8B
//      aligned, 2-way bank aliasing only = free)
//   -> L2 norm (shfl butterfly), ReLU, bf16 store / fp32 atomic readout.
// LDS = 2*64*68*2 + 4*128*4 = 19.5 KB -> 8 blocks/CU -> 100% occupancy.
// rowptr and first col load are software-pipelined across the node loop.
// ============================================================================
__global__ void __launch_bounds__(256)
sage_fused_kernel(const unsigned short* __restrict__ xb,
                  const int* __restrict__ rowptr, const int* __restrict__ col,
                  const float* __restrict__ Wl, const float* __restrict__ bl,
                  const float* __restrict__ Wr,
                  unsigned short* __restrict__ h_out,
                  const int* __restrict__ batch, float* __restrict__ out,
                  int N, int final_layer) {
    constexpr int WSS = DFEAT + 4;   // 68 ushorts = 136 B row stride
    __shared__ unsigned short WlB[DFEAT * WSS];
    __shared__ unsigned short WrB[DFEAT * WSS];
    __shared__ float feat[4][2 * DFEAT];   // per-wave: [mean | x]

    for (int t = threadIdx.x; t < DFEAT * DFEAT; t += 256) {
        int rr = t >> 6, cc = t & 63;
        WlB[rr * WSS + cc] = f2bf(Wl[t]);
        WrB[rr * WSS + cc] = f2bf(Wr[t]);
    }
    __syncthreads();   // weights ready; no barriers after this point

    const int wib  = threadIdx.x >> 6;
    const int lane = threadIdx.x & 63;
    const int r    = lane >> 4;
    const int c    = lane & 15;
    float* fm = feat[wib];
    float4* fmv = reinterpret_cast<float4*>(fm);
    const float4* fm4 = reinterpret_cast<const float4*>(fm);
    const uint2* x2 = reinterpret_cast<const uint2*>(xb);
    const uint2* wlr = reinterpret_cast<const uint2*>(&WlB[lane * WSS]);
    const uint2* wrr = reinterpret_cast<const uint2*>(&WrB[lane * WSS]);
    const float blv = bl[lane];

    const int W  = gridDim.x * 4;
    int n = blockIdx.x * 4 + wib;

    // pipeline preamble
    int st = 0, en = 0, nb = 0;
    if (n < N) {
        st = rowptr[n];
        en = rowptr[n + 1];
        int deg = en - st;
        if (deg > 0) nb = col[st + min(lane, deg - 1)];
    }

    while (n < N) {
        int nn = n + W;
        // prefetch next node's row pointers (consumed after the gather)
        int nst = 0, nen = 0;
        if (nn < N) { nst = rowptr[nn]; nen = rowptr[nn + 1]; }

        int deg = en - st;
        float4 acc = make_float4(0, 0, 0, 0);
        if (deg > 0) {
#pragma unroll
            for (int k = 0; k < 4; ++k) {            // slots 0..15 (always)
                int i = 4 * k + r;
                int q = __shfl(nb, min(i, deg - 1), 64);
                float4 v = upk4(x2[(size_t)q * 16 + c]);
                float m = (i < deg) ? 1.0f : 0.0f;
                acc.x += v.x * m; acc.y += v.y * m; acc.z += v.z * m; acc.w += v.w * m;
            }
            if (deg > 16) {
#pragma unroll
                for (int k = 4; k < 8; ++k) {
                    int i = 4 * k + r;
                    int q = __shfl(nb, min(i, deg - 1), 64);
                    float4 v = upk4(x2[(size_t)q * 16 + c]);
                    float m = (i < deg) ? 1.0f : 0.0f;
                    acc.x += v.x * m; acc.y += v.y * m; acc.z += v.z * m; acc.w += v.w * m;
                }
            }
            if (deg > 32) {
#pragma unroll
                for (int k = 8; k < 16; ++k) {
                    int i = 4 * k + r;
                    int q = __shfl(nb, min(i, deg - 1), 64);
                    float4 v = upk4(x2[(size_t)q * 16 + c]);
                    float m = (i < deg) ? 1.0f : 0.0f;
                    acc.x += v.x * m; acc.y += v.y * m; acc.z += v.z * m; acc.w += v.w * m;
                }
            }
            for (int base = 64; base < deg; base += 64) {   // ultra-rare tail
                int cnt = deg - base;
                int nb2 = col[st + base + min(lane, cnt - 1)];
#pragma unroll
                for (int k = 0; k < 16; ++k) {
                    int i = 4 * k + r;
                    int q = __shfl(nb2, min(i, cnt - 1), 64);
                    float4 v = upk4(x2[(size_t)q * 16 + c]);
                    float m = (i < cnt) ? 1.0f : 0.0f;
                    acc.x += v.x * m; acc.y += v.y * m; acc.z += v.z * m; acc.w += v.w * m;
                }
            }
        }

        // prefetch next node's first col vector (hidden under matvec below)
        int nnb = 0;
        {
            int ndeg = nen - nst;
            if (nn < N && ndeg > 0) nnb = col[nst + min(lane, ndeg - 1)];
        }

        // reduce across neighbor-slot groups (lane bits 4,5)
#pragma unroll
        for (int off = 16; off <= 32; off <<= 1) {
            acc.x += __shfl_xor(acc.x, off, 64);
            acc.y += __shfl_xor(acc.y, off, 64);
            acc.z += __shfl_xor(acc.z, off, 64);
            acc.w += __shfl_xor(acc.w, off, 64);
        }
        float inv = (deg > 0) ? 1.0f / (float)deg : 0.0f;
        if (r == 0) {       // mean row
            fmv[c] = make_float4(acc.x * inv, acc.y * inv, acc.z * inv, acc.w * inv);
        }
        if (r == 1) {       // root row
            fmv[16 + c] = upk4(x2[(size_t)n * 16 + c]);
        }
        // (same-wave LDS write->read: compiler inserts lgkmcnt wait)

        float a = blv;
#pragma unroll
        for (int j = 0; j < 16; ++j) {
            float4 w1 = upk4(wlr[j]);
            float4 w2 = upk4(wrr[j]);
            float4 f1 = fm4[j];        // broadcast
            float4 f2 = fm4[16 + j];
            a += f1.x * w1.x + f1.y * w1.y + f1.z * w1.z + f1.w * w1.w
               + f2.x * w2.x + f2.y * w2.y + f2.z * w2.z + f2.w * w2.w;
        }
        float ss = a * a;
#pragma unroll
        for (int off = 32; off; off >>= 1) ss += __shfl_xor(ss, off, 64);
        float o = fmaxf(a / fmaxf(sqrtf(ss), 1e-12f), 0.0f);

        if (final_layer) {
            atomicAdd(&out[(size_t)batch[n] * DFEAT + lane], o);
        } else {
            h_out[(size_t)n * DFEAT + lane] = f2bf(o);
        }

        n = nn; st = nst; en = nen; nb = nnb;
    }
}

// ============================================================================
extern "C" void kernel_launch(void* const* d_in, const int* in_sizes, int n_in,
                              void* d_out, int out_size, void* d_ws, size_t ws_size,
                              hipStream_t stream) {
    const float* x_raw = (const float*)d_in[0];
    const int*   eidx  = (const int*)d_in[1];
    const int*   batch = (const int*)d_in[2];
    const float* Wl0 = (const float*)d_in[3];
    const float* bl0 = (const float*)d_in[4];
    const float* Wr0 = (const float*)d_in[5];
    const float* Wl1 = (const float*)d_in[6];
    const float* bl1 = (const float*)d_in[7];
    const float* Wr1 = (const float*)d_in[8];
    const float* Wl2 = (const float*)d_in[9];
    const float* bl2 = (const float*)d_in[10];
    const float* Wr2 = (const float*)d_in[11];

    const int N = in_sizes[0] / DFEAT;
    const int E = in_sizes[1] / 2;
    const int* srcs = eidx;
    const int* dsts = eidx + E;
    float* out = (float*)d_out;

    const int nb = (N + 1023) / 1024;

    char* ws = (char*)d_ws;
    auto align512 = [](size_t v) { return (v + 511) & ~(size_t)511; };
    size_t off = 0;
    int* degi   = (int*)(ws + off); off += align512((size_t)N * 4);
    int* rowptr = (int*)(ws + off); off += align512(((size_t)N + 1) * 4);
    int* cursor = (int*)(ws + off); off += align512((size_t)N * 4);
    int* bsum   = (int*)(ws + off); off += align512((size_t)nb * 4);
    int* col    = (int*)(ws + off); off += align512((size_t)E * 4);
    unsigned short* xb = (unsigned short*)(ws + off); off += align512((size_t)N * DFEAT * 2);
    unsigned short* hA = (unsigned short*)(ws + off); off += align512((size_t)N * DFEAT * 2);
    unsigned short* hB = (unsigned short*)(ws + off);

    hipMemsetAsync(degi, 0, (size_t)N * 4, stream);
    hipMemsetAsync(out, 0, (size_t)out_size * 4, stream);

    const int n4 = N * DFEAT / 4;
    cvt_bf16_kernel<<<(n4 + 255) / 256, 256, 0, stream>>>(x_raw, xb, n4);

    deg_count_kernel<<<(E + 255) / 256, 256, 0, stream>>>(dsts, degi, E);
    block_sum_kernel<<<nb, 1024, 0, stream>>>(degi, bsum, N);
    scan_bsum_kernel<<<1, 64, 0, stream>>>(bsum, nb);
    scan_final_kernel<<<nb, 1024, 0, stream>>>(degi, bsum, rowptr, cursor, N);

    // partitioned fill: 8 sequential dst-range passes
    const int NPASS = 8;
    const int rng = (N + NPASS - 1) / NPASS;
    for (int p = 0; p < NPASS; ++p) {
        int lo = p * rng;
        int hi = min(N, lo + rng);
        fill_pass_kernel<<<(E + 255) / 256, 256, 0, stream>>>(srcs, dsts, cursor,
                                                              col, E, lo, hi);
    }

    const int layerBlocks = 2048;   // 8 blocks/CU (LDS-capped), wave per node

    sage_fused_kernel<<<layerBlocks, 256, 0, stream>>>(xb, rowptr, col,
        Wl0, bl0, Wr0, hA, nullptr, nullptr, N, 0);
    sage_fused_kernel<<<layerBlocks, 256, 0, stream>>>(hA, rowptr, col,
        Wl1, bl1, Wr1, hB, nullptr, nullptr, N, 0);
    sage_fused_kernel<<<layerBlocks, 256, 0, stream>>>(hB, rowptr, col,
        Wl2, bl2, Wr2, nullptr, batch, out, N, 1);
}

// Round 7
// 643.769 us; speedup vs baseline: 1.1985x; 1.1985x over previous
//
#include <hip/hip_runtime.h>

#define DFEAT 64

// ---------------- bf16 helpers (OCP bfloat16, RNE pack) ----------------
__device__ __forceinline__ float bfhi(unsigned int u) {
    return __builtin_bit_cast(float, u & 0xFFFF0000u);
}
__device__ __forceinline__ float bflo(unsigned int u) {
    return __builtin_bit_cast(float, u << 16);
}
__device__ __forceinline__ unsigned short f2bf(float f) { // RNE
    unsigned int u = __builtin_bit_cast(unsigned int, f);
    u += 0x7FFFu + ((u >> 16) & 1u);
    return (unsigned short)(u >> 16);
}
__device__ __forceinline__ float4 upk4(uint2 v) {
    float4 r;
    r.x = bflo(v.x); r.y = bfhi(v.x);
    r.z = bflo(v.y); r.w = bfhi(v.y);
    return r;
}

// ============================================================================
// fp32 -> bf16 conversion of the input features (once per call)
// ============================================================================
__global__ void __launch_bounds__(256)
cvt_bf16_kernel(const float* __restrict__ in, unsigned short* __restrict__ outb,
                int n4) {
    int i = blockIdx.x * 256 + threadIdx.x;
    if (i >= n4) return;
    const float4 v = reinterpret_cast<const float4*>(in)[i];
    uint2 p;
    p.x = (unsigned int)f2bf(v.x) | ((unsigned int)f2bf(v.y) << 16);
    p.y = (unsigned int)f2bf(v.z) | ((unsigned int)f2bf(v.w) << 16);
    reinterpret_cast<uint2*>(outb)[i] = p;
}

// ============================================================================
// CSR build (once per call; edge_index shared by all 3 layers)
// ============================================================================
__global__ void __launch_bounds__(256)
deg_count_kernel(const int* __restrict__ dsts, int* __restrict__ degi, int E) {
    int e = blockIdx.x * 256 + threadIdx.x;
    if (e < E) atomicAdd(&degi[dsts[e]], 1);
}

__global__ void __launch_bounds__(1024)
block_sum_kernel(const int* __restrict__ degi, int* __restrict__ bsum, int N) {
    __shared__ int sm[1024];
    int idx = blockIdx.x * 1024 + threadIdx.x;
    sm[threadIdx.x] = (idx < N) ? degi[idx] : 0;
    __syncthreads();
    for (int s = 512; s > 0; s >>= 1) {
        if (threadIdx.x < s) sm[threadIdx.x] += sm[threadIdx.x + s];
        __syncthreads();
    }
    if (threadIdx.x == 0) bsum[blockIdx.x] = sm[0];
}

__global__ void __launch_bounds__(64)
scan_bsum_kernel(int* __restrict__ bsum, int nb) {
    if (threadIdx.x == 0 && blockIdx.x == 0) {
        int run = 0;
        for (int i = 0; i < nb; ++i) { int v = bsum[i]; bsum[i] = run; run += v; }
    }
}

__global__ void __launch_bounds__(1024)
scan_final_kernel(const int* __restrict__ degi, const int* __restrict__ bsum,
                  int* __restrict__ rowptr, int* __restrict__ cursor, int N) {
    __shared__ int sm[1024];
    int idx = blockIdx.x * 1024 + threadIdx.x;
    int v = (idx < N) ? degi[idx] : 0;
    sm[threadIdx.x] = v;
    __syncthreads();
    for (int s = 1; s < 1024; s <<= 1) {
        int t = (threadIdx.x >= s) ? sm[threadIdx.x - s] : 0;
        __syncthreads();
        sm[threadIdx.x] += t;
        __syncthreads();
    }
    int excl = bsum[blockIdx.x] + sm[threadIdx.x] - v;
    if (idx < N) { rowptr[idx] = excl; cursor[idx] = excl; }
    if (idx == N - 1) rowptr[N] = excl + v;
}

// Partitioned fill (R6-verified win): pass p only handles dst in [lo,hi) ->
// active col slice ~800 KB -> all ~16 writes to a 64B line land in one short
// epoch -> L2 write-combines (WRITE_SIZE collapsed 105 MB -> ~nothing).
// Edge-list re-reads hit L2/L3 after pass 0.
__global__ void __launch_bounds__(256)
fill_pass_kernel(const int* __restrict__ srcs, const int* __restrict__ dsts,
                 int* __restrict__ cursor, int* __restrict__ col, int E,
                 int lo, int hi) {
    int e = blockIdx.x * 256 + threadIdx.x;
    if (e < E) {
        int d = dsts[e];
        if (d >= lo && d < hi) {
            int pos = atomicAdd(&cursor[d], 1);
            col[pos] = srcs[e];
        }
    }
}

// ============================================================================
// Gather-mean over bf16 rows (128 B). One wave per node, NO LDS, NO barriers
// (R4-verified: free-running waves beat any fused/barriered variant).
// r=lane>>4 (neighbor slot), c=lane&15 (uint2 chunk). fp32 accumulate.
// ============================================================================
__global__ void __launch_bounds__(256)
gather_mean_kernel(const unsigned short* __restrict__ xb,
                   const int* __restrict__ rowptr, const int* __restrict__ col,
                   unsigned short* __restrict__ meanb, int N) {
    int w = (blockIdx.x * 256 + threadIdx.x) >> 6;
    if (w >= N) return;
    const int lane = threadIdx.x & 63;
    const int r = lane >> 4;
    const int c = lane & 15;
    const uint2* x2 = reinterpret_cast<const uint2*>(xb);
    uint2* mean2 = reinterpret_cast<uint2*>(meanb);

    int st = rowptr[w], en = rowptr[w + 1];
    int deg = en - st;

    if (deg == 0) {
        if (r == 0) mean2[(size_t)w * 16 + c] = make_uint2(0, 0);
        return;
    }

    int nb = col[st + min(lane, deg - 1)];
    float4 acc = make_float4(0, 0, 0, 0);

#pragma unroll
    for (int k = 0; k < 4; ++k) {            // slots 0..15 (always)
        int i = 4 * k + r;
        int q = __shfl(nb, min(i, deg - 1), 64);
        float4 v = upk4(x2[(size_t)q * 16 + c]);
        float m = (i < deg) ? 1.0f : 0.0f;
        acc.x += v.x * m; acc.y += v.y * m; acc.z += v.z * m; acc.w += v.w * m;
    }
    if (deg > 16) {                          // slots 16..31
#pragma unroll
        for (int k = 4; k < 8; ++k) {
            int i = 4 * k + r;
            int q = __shfl(nb, min(i, deg - 1), 64);
            float4 v = upk4(x2[(size_t)q * 16 + c]);
            float m = (i < deg) ? 1.0f : 0.0f;
            acc.x += v.x * m; acc.y += v.y * m; acc.z += v.z * m; acc.w += v.w * m;
        }
    }
    if (deg > 32) {                          // slots 32..63 (rare)
#pragma unroll
        for (int k = 8; k < 16; ++k) {
            int i = 4 * k + r;
            int q = __shfl(nb, min(i, deg - 1), 64);
            float4 v = upk4(x2[(size_t)q * 16 + c]);
            float m = (i < deg) ? 1.0f : 0.0f;
            acc.x += v.x * m; acc.y += v.y * m; acc.z += v.z * m; acc.w += v.w * m;
        }
    }
    for (int base = 64; base < deg; base += 64) {   // ultra-rare tail
        int cnt = deg - base;
        int nb2 = col[st + base + min(lane, cnt - 1)];
#pragma unroll
        for (int k = 0; k < 16; ++k) {
            int i = 4 * k + r;
            int q = __shfl(nb2, min(i, cnt - 1), 64);
            float4 v = upk4(x2[(size_t)q * 16 + c]);
            float m = (i < cnt) ? 1.0f : 0.0f;
            acc.x += v.x * m; acc.y += v.y * m; acc.z += v.z * m; acc.w += v.w * m;
        }
    }

#pragma unroll
    for (int off = 16; off <= 32; off <<= 1) {
        acc.x += __shfl_xor(acc.x, off, 64);
        acc.y += __shfl_xor(acc.y, off, 64);
        acc.z += __shfl_xor(acc.z, off, 64);
        acc.w += __shfl_xor(acc.w, off, 64);
    }
    float inv = 1.0f / (float)deg;
    if (r == 0) {
        uint2 p;
        p.x = (unsigned int)f2bf(acc.x * inv) | ((unsigned int)f2bf(acc.y * inv) << 16);
        p.y = (unsigned int)f2bf(acc.z * inv) | ((unsigned int)f2bf(acc.w * inv) << 16);
        mean2[(size_t)w * 16 + c] = p;
    }
}

// ============================================================================
// Transform: out = mean@Wl.T + bl + x@Wr.T; L2norm; ReLU.
// Weights bf16 in LDS (stride 68 ushort = 136 B rows; uint2 reads, 2-way bank
// aliasing = free): total LDS 21.4 KB -> 7 blocks/CU (vs 4 with fp32).
// ============================================================================
__global__ void __launch_bounds__(256)
transform_kernel(const unsigned short* __restrict__ xb,
                 const unsigned short* __restrict__ meanb,
                 const float* __restrict__ Wl, const float* __restrict__ bl,
                 const float* __restrict__ Wr,
                 unsigned short* __restrict__ h_out,
                 const int* __restrict__ batch, float* __restrict__ out,
                 int n_nodes, int final_layer) {
    constexpr int WSS = DFEAT + 4;   // 68 ushorts
    __shared__ unsigned short WlB[DFEAT * WSS];
    __shared__ unsigned short WrB[DFEAT * WSS];
    __shared__ float feat[4][4 * DFEAT];   // [meanA | xA | meanB | xB] fp32

    for (int t = threadIdx.x; t < DFEAT * DFEAT; t += 256) {
        int rr = t >> 6, cc = t & 63;
        WlB[rr * WSS + cc] = f2bf(Wl[t]);
        WrB[rr * WSS + cc] = f2bf(Wr[t]);
    }
    __syncthreads();

    const int wib  = threadIdx.x >> 6;
    const int lane = threadIdx.x & 63;
    const int g    = lane >> 4;     // 0:meanA 1:xA 2:meanB 3:xB
    const int c    = lane & 15;
    float* fm = feat[wib];
    float4* fmv = reinterpret_cast<float4*>(fm);
    const uint2* x2 = reinterpret_cast<const uint2*>(xb);
    const uint2* mean2 = reinterpret_cast<const uint2*>(meanb);
    const uint2* wlr = reinterpret_cast<const uint2*>(&WlB[lane * WSS]);
    const uint2* wrr = reinterpret_cast<const uint2*>(&WrB[lane * WSS]);
    const float4* fm4 = reinterpret_cast<const float4*>(fm);
    const float blv = bl[lane];

    const int P      = (n_nodes + 1) >> 1;
    const int nwaves = gridDim.x * 4;
    const int gwave  = blockIdx.x * 4 + wib;
    const int iters  = (P + nwaves - 1) / nwaves;   // uniform trip count

    for (int it = 0; it < iters; ++it) {
        int p = gwave + it * nwaves;
        bool actp = (p < P);
        int n0 = 2 * p;
        int n1 = 2 * p + 1;
        bool act1 = actp && (n1 < n_nodes);
        int n1c = act1 ? n1 : n0;

        if (actp) {
            int node = (g & 2) ? n1c : n0;
            const uint2* srcp = (g & 1) ? x2 : mean2;
            fmv[lane] = upk4(srcp[(size_t)node * 16 + c]);
        }
        __syncthreads();

        if (actp) {
            float accA = blv, accB = blv;
#pragma unroll
            for (int j = 0; j < DFEAT / 4; ++j) {
                float4 w1 = upk4(wlr[j]);
                float4 w2 = upk4(wrr[j]);
                float4 a1 = fm4[j];
                float4 a2 = fm4[16 + j];
                float4 b1 = fm4[32 + j];
                float4 b2 = fm4[48 + j];
                accA += a1.x * w1.x + a1.y * w1.y + a1.z * w1.z + a1.w * w1.w
                      + a2.x * w2.x + a2.y * w2.y + a2.z * w2.z + a2.w * w2.w;
                accB += b1.x * w1.x + b1.y * w1.y + b1.z * w1.z + b1.w * w1.w
                      + b2.x * w2.x + b2.y * w2.y + b2.z * w2.z + b2.w * w2.w;
            }
            float ssA = accA * accA, ssB = accB * accB;
#pragma unroll
            for (int off = 32; off; off >>= 1) {
                ssA += __shfl_xor(ssA, off, 64);
                ssB += __shfl_xor(ssB, off, 64);
            }
            float oA = fmaxf(accA / fmaxf(sqrtf(ssA), 1e-12f), 0.0f);
            float oB = fmaxf(accB / fmaxf(sqrtf(ssB), 1e-12f), 0.0f);

            if (final_layer) {
                atomicAdd(&out[(size_t)batch[n0] * DFEAT + lane], oA);
                if (act1) atomicAdd(&out[(size_t)batch[n1] * DFEAT + lane], oB);
            } else {
                h_out[(size_t)n0 * DFEAT + lane] = f2bf(oA);
                if (act1) h_out[(size_t)n1 * DFEAT + lane] = f2bf(oB);
            }
        }
        __syncthreads();
    }
}

// ============================================================================
extern "C" void kernel_launch(void* const* d_in, const int* in_sizes, int n_in,
                              void* d_out, int out_size, void* d_ws, size_t ws_size,
                              hipStream_t stream) {
    const float* x_raw = (const float*)d_in[0];
    const int*   eidx  = (const int*)d_in[1];
    const int*   batch = (const int*)d_in[2];
    const float* Wl0 = (const float*)d_in[3];
    const float* bl0 = (const float*)d_in[4];
    const float* Wr0 = (const float*)d_in[5];
    const float* Wl1 = (const float*)d_in[6];
    const float* bl1 = (const float*)d_in[7];
    const float* Wr1 = (const float*)d_in[8];
    const float* Wl2 = (const float*)d_in[9];
    const float* bl2 = (const float*)d_in[10];
    const float* Wr2 = (const float*)d_in[11];

    const int N = in_sizes[0] / DFEAT;
    const int E = in_sizes[1] / 2;
    const int* srcs = eidx;
    const int* dsts = eidx + E;
    float* out = (float*)d_out;

    const int nb = (N + 1023) / 1024;

    char* ws = (char*)d_ws;
    auto align512 = [](size_t v) { return (v + 511) & ~(size_t)511; };
    size_t off = 0;
    int* degi   = (int*)(ws + off); off += align512((size_t)N * 4);
    int* rowptr = (int*)(ws + off); off += align512(((size_t)N + 1) * 4);
    int* cursor = (int*)(ws + off); off += align512((size_t)N * 4);
    int* bsum   = (int*)(ws + off); off += align512((size_t)nb * 4);
    int* col    = (int*)(ws + off); off += align512((size_t)E * 4);
    unsigned short* xb    = (unsigned short*)(ws + off); off += align512((size_t)N * DFEAT * 2);
    unsigned short* meanb = (unsigned short*)(ws + off); off += align512((size_t)N * DFEAT * 2);
    unsigned short* hA    = (unsigned short*)(ws + off); off += align512((size_t)N * DFEAT * 2);
    unsigned short* hB    = (unsigned short*)(ws + off);

    hipMemsetAsync(degi, 0, (size_t)N * 4, stream);
    hipMemsetAsync(out, 0, (size_t)out_size * 4, stream);

    const int n4 = N * DFEAT / 4;
    cvt_bf16_kernel<<<(n4 + 255) / 256, 256, 0, stream>>>(x_raw, xb, n4);

    deg_count_kernel<<<(E + 255) / 256, 256, 0, stream>>>(dsts, degi, E);
    block_sum_kernel<<<nb, 1024, 0, stream>>>(degi, bsum, N);
    scan_bsum_kernel<<<1, 64, 0, stream>>>(bsum, nb);
    scan_final_kernel<<<nb, 1024, 0, stream>>>(degi, bsum, rowptr, cursor, N);

    // partitioned fill: 8 sequential dst-range passes (R6-verified win)
    const int NPASS = 8;
    const int rng = (N + NPASS - 1) / NPASS;
    for (int p = 0; p < NPASS; ++p) {
        int lo = p * rng;
        int hi = min(N, lo + rng);
        fill_pass_kernel<<<(E + 255) / 256, 256, 0, stream>>>(srcs, dsts, cursor,
                                                              col, E, lo, hi);
    }

    const int gatherBlocks = (N + 3) / 4;   // one wave per node
    const int xfBlocks     = 2048;          // grid-stride over node pairs

    // ---- layer 0
    gather_mean_kernel<<<gatherBlocks, 256, 0, stream>>>(xb, rowptr, col, meanb, N);
    transform_kernel<<<xfBlocks, 256, 0, stream>>>(xb, meanb, Wl0, bl0, Wr0,
                                                   hA, nullptr, nullptr, N, 0);
    // ---- layer 1
    gather_mean_kernel<<<gatherBlocks, 256, 0, stream>>>(hA, rowptr, col, meanb, N);
    transform_kernel<<<xfBlocks, 256, 0, stream>>>(hA, meanb, Wl1, bl1, Wr1,
                                                   hB, nullptr, nullptr, N, 0);
    // ---- layer 2
    gather_mean_kernel<<<gatherBlocks, 256, 0, stream>>>(hB, rowptr, col, meanb, N);
    transform_kernel<<<xfBlocks, 256, 0, stream>>>(hB, meanb, Wl2, bl2, Wr2,
                                                   nullptr, batch, out, N, 1);
}